// Round 15
// baseline (225.187 us; speedup 1.0000x reference)
//
#include <hip/hip_runtime.h>
#include <hip/hip_bf16.h>
#include <stdint.h>

#define BB 32
#define GG 100
#define AA 8400
#define TPB 256
#define NCH 33                         // ceil(8400/256) chunks per image
#define TPK 512
#define MAXJ 17                        // ceil(8400/512) slots per thread (max)
#define BA (BB*AA)
#define NG (BB*GG)
#define NBLK (BA/TPB)                  // 1050 kCD blocks

typedef __hip_bfloat16 bf16;

struct P {
  const void *outs, *labs, *ss;
  float4 *box4, *meta4, *gtb, *gtc;   // per-anchor box/meta; per-gt box/center
  float4 *cbox, *cmeta;               // per-image compacted fg anchors
  float *miou, *pb, *pf;              // per-block BCE / fg partials (no atomics)
  int *cnt, *gmax, *nfg, *chunkcnt;
  float *out;
};

// runtime input-dtype detection: strides[0]==8.0
// f32 word 0x41000000 ; bf16 pair (8.0,8.0) 0x41004100
__device__ __forceinline__ int dtypeFlag(const void* ss){
  return (((const uint32_t*)ss)[0] == 0x41000000u) ? 1 : 0;
}
__device__ __forceinline__ float ld(const void* p, int i, int isf32){
  return isf32 ? ((const float*)p)[i] : __bfloat162float(((const bf16*)p)[i]);
}
// analytic anchor geometry (exact: ints + pow2 strides exact in f32/bf16)
__device__ __forceinline__ void ageom(int a, float& xc, float& yc, float& r){
  int x, y, s;
  if (a < 6400){ x = a % 80; y = a / 80; s = 8; }
  else if (a < 8000){ int q = a - 6400; x = q % 40; y = q / 40; s = 16; }
  else { int q = a - 8000; x = q % 20; y = q / 20; s = 32; }
  float fs = (float)s;
  xc = ((float)x + 0.5f) * fs;
  yc = ((float)y + 0.5f) * fs;
  r  = 2.5f * fs;
}
__device__ __forceinline__ uint32_t apack(int a){
  int x, y, s;
  if (a < 6400){ x = a % 80; y = a / 80; s = 8; }
  else if (a < 8000){ int q = a - 6400; x = q % 40; y = q / 40; s = 16; }
  else { int q = a - 8000; x = q % 20; y = q / 20; s = 32; }
  uint32_t ix = (uint32_t)(x*s + s/2), iy = (uint32_t)(y*s + s/2);
  return ix | (iy << 16);
}

// ---- kA: gt structs (self-computed) + per-anchor staging + fg + chunk count
__global__ __launch_bounds__(TPB) void kA(P p){
  __shared__ float4 s_gtb[GG], s_gtc[GG];
  __shared__ float s_o[TPB*6];
  __shared__ int s_w[4];
  __shared__ int s_ng;
  int t = threadIdx.x;
  int c = blockIdx.x, b = blockIdx.y;
  int isf = dtypeFlag(p.ss);
  if (t == 0) s_ng = 0;
  int nel = min(TPB*6, AA*6 - c*(TPB*6));      // floats in this chunk
  if (isf){
    const float4* src = (const float4*)((const float*)p.outs + (size_t)b*AA*6 + (size_t)c*(TPB*6));
    float4* dst = (float4*)s_o;
    for (int i = t; i < nel/4; i += TPB) dst[i] = src[i];
  } else {
    const uint4* src = (const uint4*)((const bf16*)p.outs + (size_t)b*AA*6 + (size_t)c*(TPB*6));
    for (int i = t; i < nel/8; i += TPB){
      uint4 u = src[i];
      int o = i*8;
      s_o[o+0]=__uint_as_float(u.x<<16); s_o[o+1]=__uint_as_float(u.x&0xffff0000u);
      s_o[o+2]=__uint_as_float(u.y<<16); s_o[o+3]=__uint_as_float(u.y&0xffff0000u);
      s_o[o+4]=__uint_as_float(u.z<<16); s_o[o+5]=__uint_as_float(u.z&0xffff0000u);
      s_o[o+6]=__uint_as_float(u.w<<16); s_o[o+7]=__uint_as_float(u.w&0xffff0000u);
    }
  }
  __syncthreads();
  if (t < GG){
    int i = b*GG + t;
    float l0 = ld(p.labs, i*5  , isf);
    float gcx= ld(p.labs, i*5+1, isf);
    float gcy= ld(p.labs, i*5+2, isf);
    float gw = ld(p.labs, i*5+3, isf);
    float gh = ld(p.labs, i*5+4, isf);
    int valid = (l0+gcx+gcy+gw+gh) > 0.f;
    float4 vb = make_float4(gcx-gw*0.5f, gcy-gh*0.5f, gcx+gw*0.5f, gcy+gh*0.5f);
    float4 vc = make_float4(gcx, gcy, gw*gh, valid ? 1.f : 0.f);
    s_gtb[t] = vb; s_gtc[t] = vc;
    if (c == 0){ p.gtb[i] = vb; p.gtc[i] = vc; }
    if (valid) atomicMax(&s_ng, t+1);
  }
  __syncthreads();
  int ng = s_ng;
  if (c == 0 && t == 0) p.gmax[b] = ng;
  int a = c*TPB + t;
  int fg = 0;
  if (a < AA){
    float cx=s_o[t*6], cy=s_o[t*6+1], w=s_o[t*6+2], h=s_o[t*6+3], ob=s_o[t*6+4], cl=s_o[t*6+5];
    int idx = b*AA + a;
    p.box4[idx] = make_float4(cx-w*0.5f, cy-h*0.5f, cx+w*0.5f, cy+h*0.5f);
    float so = 1.f/(1.f+expf(-ob));
    float sc = 1.f/(1.f+expf(-cl));
    float pcc = -logf(sqrtf(sc*so) + 1e-9f);
    float xc, yc, r; ageom(a, xc, yc, r);
    for (int g = 0; g < ng; ++g){
      float4 gb = s_gtb[g], gc = s_gtc[g];
      bool inb = (xc>gb.x)&&(xc<gb.z)&&(yc>gb.y)&&(yc<gb.w);
      bool inc = (fabsf(xc-gc.x)<r)&&(fabsf(yc-gc.y)<r);
      fg |= (gc.w != 0.f) && (inb||inc);
    }
    p.meta4[idx] = make_float4(w*h, pcc, fg ? 1.f : 0.f, cl);
    p.cnt[idx] = 0;
  }
  int lane = t & 63, wid = t >> 6;
  unsigned long long m = __ballot(fg);
  if (lane == 0) s_w[wid] = __popcll(m);
  __syncthreads();
  if (t == 0) p.chunkcnt[b*NCH + c] = s_w[0]+s_w[1]+s_w[2]+s_w[3];
}

// ---- kE: parallel order-preserving fg compaction (one block per chunk) -----
__global__ __launch_bounds__(TPB) void kE(P p){
  __shared__ int s_off;
  __shared__ int s_w[4];
  int t = threadIdx.x, c = blockIdx.x, b = blockIdx.y;
  int lane = t & 63, wid = t >> 6;
  if (wid == 0){
    int v = (lane < c) ? p.chunkcnt[b*NCH + lane] : 0;   // c <= 32 < 64 lanes
#pragma unroll
    for (int off=32; off; off>>=1) v += __shfl_xor(v, off);
    if (lane == 0) s_off = v;
  }
  int a = c*TPB + t;
  float4 mt = make_float4(0,0,0,0);
  int fg = 0;
  if (a < AA){ mt = p.meta4[b*AA+a]; fg = (mt.z != 0.f) ? 1 : 0; }
  unsigned long long m = __ballot(fg);
  int rank = __popcll(m & ((1ull<<lane)-1ull));
  if (lane == 0) s_w[wid] = __popcll(m);
  __syncthreads();
  int off = s_off;
  for (int w2 = 0; w2 < wid; ++w2) off += s_w[w2];
  if (fg){
    int pos = off + rank;
    p.cbox [b*AA+pos] = p.box4[b*AA+a];
    // cmeta: (area, pcc, a, packed int centers)
    p.cmeta[b*AA+pos] = make_float4(mt.x, mt.y, __int_as_float(a),
                                    __uint_as_float(apack(a)));
  }
  if (c == NCH-1 && t == 0)
    p.nfg[b] = s_off + s_w[0]+s_w[1]+s_w[2]+s_w[3];
}

// ---- kB: per-(b,g) dyn_k + selection; wave-local extraction + 1 merge ------
// 4 barriers total; all 8 waves pop their own regions barrier-free.
__global__ __launch_bounds__(TPK) void kB(P p){
  __shared__ float s_slot[MAXJ*TPK];   // 34.8 KB: [j*TPK + t] thread-private cols
  __shared__ float s_i10[8*10];        // per-wave descending iou top-10
  __shared__ float s_c10[8*10];        // per-wave ascending (cost,pos) top-dk
  __shared__ int   s_ci10[8*10];
  __shared__ int   s_selA[10];
  __shared__ float s_sum;
  int t = threadIdx.x;
  int b = blockIdx.x / GG, g = blockIdx.x % GG;
  float4 gc = p.gtc[b*GG+g];
  if (gc.w == 0.f) return;                 // uniform, pre-barrier
  float4 gb = p.gtb[b*GG+g];
  float glx=gb.x, gly=gb.y, ghx=gb.z, ghy=gb.w, gcx=gc.x, gcy=gc.y, ga=gc.z;
  int base = b*AA;
  int nfg = p.nfg[b];
  int nj = (nfg + TPK - 1) / TPK;          // runtime bound (~6)
  int lane = t & 63, wid = t >> 6;
  if (t < 10) s_selA[t] = -1;
  if (lane < 10){                          // own-wave strip init (no hazard)
    s_i10[wid*10+lane] = -3.0e38f;
    s_c10[wid*10+lane] = 3.0e38f;
    s_ci10[wid*10+lane] = 0x7fffffff;
  }

  // main pass: iou into LDS column slots (store-then-extract; no sorting)
  float lmax = -1.f;
  for (int j=0;j<nj;j++){
    int pos = j*TPK + t;
    float v = -1.f;
    if (pos < nfg){
      float4 mt = p.cmeta[base+pos];
      float4 bx = p.cbox [base+pos];
      float tlx=fmaxf(glx,bx.x), tly=fmaxf(gly,bx.y);
      float brx=fminf(ghx,bx.z), bry=fminf(ghy,bx.w);
      float iw=fmaxf(brx-tlx,0.f), ih=fmaxf(bry-tly,0.f);
      float inter=iw*ih;
      v = inter/(ga + mt.x - inter + 1e-12f);
    }
    s_slot[pos] = v;
    lmax = fmaxf(lmax, v);
  }

  // phase 1 (wave-local, barrier-free): this wave's top-10 ious, descending
  for (int k=0;k<10;k++){
    float wv = lmax;
#pragma unroll
    for (int off=32; off; off>>=1) wv = fmaxf(wv, __shfl_xor(wv, off));
    if (wv <= 0.f) break;                  // remaining are zeros/invalid
    if (lane == 0) s_i10[wid*10+k] = wv;
    unsigned long long ms = __ballot(lmax == wv);
    if ((int)(__ffsll(ms) - 1) == lane){   // unique owner: flip + refresh own cols
      int pm = -1; float nl = -1.f;
      for (int j=0;j<nj;j++){
        int pos = j*TPK+t;
        float vv = s_slot[pos];
        if (pm < 0 && vv == wv){ pm = pos; vv = -wv; s_slot[pos] = vv; }
        nl = fmaxf(nl, vv);
      }
      lmax = nl;
    }
  }
  __syncthreads();                         // B1: strips ready
  if (wid == 0){                           // 8-way sorted merge, descending sum
    int h = 0;
    float val = (lane < 8) ? s_i10[lane*10] : -3.0e38f;
    float sum = 0.f;
    for (int k=0;k<10;k++){
      float gv = val;
#pragma unroll
      for (int off=32; off; off>>=1) gv = fmaxf(gv, __shfl_xor(gv, off));
      if (gv <= 0.f) break;
      sum += gv;                           // descending == jnp top_k sum order
      unsigned long long ms = __ballot(val == gv);
      if ((int)(__ffsll(ms) - 1) == lane){
        h++;
        val = (h < 10) ? s_i10[lane*10+h] : -3.0e38f;
      }
    }
    if (lane == 0) s_sum = sum;
  }
  __syncthreads();                         // B2: dk visible
  int dk = (int)s_sum; if (dk<1) dk=1; if (dk>10) dk=10;

  // phase 2: recompute cost into same slots (iou = |slot|, bit-exact)
  float lcv = 3.0e38f; int lci = 0x7fffffff;
  for (int j=0;j<nj;j++){
    int pos = j*TPK + t;
    float cst = 3.0e38f;
    if (pos < nfg){
      float iou = fabsf(s_slot[pos]);
      float4 mt = p.cmeta[base+pos];
      uint32_t u = __float_as_uint(mt.w);
      float xc = (float)(u & 0xffffu), yc = (float)(u >> 16);
      int a = __float_as_int(mt.z);
      float r = (a < 6400) ? 20.f : ((a < 8000) ? 40.f : 80.f);
      bool inb=(xc>glx)&&(xc<ghx)&&(yc>gly)&&(yc<ghy);
      bool inc=(fabsf(xc-gcx)<r)&&(fabsf(yc-gcy)<r);
      cst = mt.y + 3.f*(-logf(iou+1e-8f)) + ((inb&&inc)?0.f:100000.f);
    }
    s_slot[pos] = cst;
    if (cst < lcv){ lcv = cst; lci = pos; }    // asc pos => first-tie kept
  }
  // wave-local ascending top-dk (cost,pos); pos unique => exact stable order
  for (int k=0;k<dk;k++){
    float wv = lcv; int wi = lci;
#pragma unroll
    for (int off=32; off; off>>=1){
      float ov=__shfl_xor(wv,off); int oi=__shfl_xor(wi,off);
      if (ov<wv || (ov==wv && oi<wi)){ wv=ov; wi=oi; }
    }
    if (wv >= 2.9e38f) break;              // wave region exhausted
    if (lane == 0){ s_c10[wid*10+k] = wv; s_ci10[wid*10+k] = wi; }
    if (lci == wi){                        // unique owner: pop + refresh own cols
      s_slot[wi] = 3.0e38f;
      float nv = 3.0e38f; int ni = 0x7fffffff;
      for (int j=0;j<nj;j++){
        int pos = j*TPK+t;
        float vv = s_slot[pos];
        if (vv < nv){ nv=vv; ni=pos; }
      }
      lcv = nv; lci = ni;
    }
  }
  __syncthreads();                         // B3: cost strips ready
  if (wid == 0){                           // 8-way lex merge, dk rounds
    int h = 0;
    float val = (lane < 8) ? s_c10[lane*10] : 3.0e38f;
    int   vi  = (lane < 8) ? s_ci10[lane*10] : 0x7fffffff;
    for (int k=0;k<dk;k++){
      float gv = val; int gi = vi;
#pragma unroll
      for (int off=32; off; off>>=1){
        float ov=__shfl_xor(gv,off); int oi=__shfl_xor(gi,off);
        if (ov<gv || (ov==gv && oi<gi)){ gv=ov; gi=oi; }
      }
      if (gv >= 2.9e38f) break;
      if (lane == 0) s_selA[k] = gi;
      if (vi == gi){                       // unique owner advances its list
        h++;
        val = (h < 10) ? s_c10[lane*10+h] : 3.0e38f;
        vi  = (h < 10) ? s_ci10[lane*10+h] : 0x7fffffff;
      }
    }
  }
  __syncthreads();                         // B4: selA ready
  if (t < dk){
    int pos = s_selA[t];                   // t-th smallest (cost,pos)
    if (pos >= 0){
      float4 mt = p.cmeta[base+pos];
      float4 bx = p.cbox [base+pos];
      int a = __float_as_int(mt.z);
      float tlx=fmaxf(glx,bx.x), tly=fmaxf(gly,bx.y);
      float brx=fminf(ghx,bx.z), bry=fminf(ghy,bx.w);
      float iw=fmaxf(brx-tlx,0.f), ih=fmaxf(bry-tly,0.f);
      float inter=iw*ih;
      float iou=inter/(ga + mt.x - inter + 1e-12f);
      atomicAdd(&p.cnt[base+a], 1);
      p.miou[base+a] = iou;                // races only when cnt>1; kCD recomputes
    }
  }
}

// ---- kCD: conflict resolution + masked BCE -> per-block partials -----------
__global__ __launch_bounds__(TPB) void kCD(P p){
  int t = threadIdx.x;
  int idx = blockIdx.x*TPB + t;
  float bce=0.f, fgv=0.f;
  if (idx < BA){
    int cgt = p.cnt[idx];
    if (cgt > 0){
      int b = idx/AA, a = idx - b*AA;
      float4 mt = p.meta4[idx];
      float iouv;
      if (cgt == 1){ iouv = p.miou[idx]; }
      else {
        float4 bx = p.box4[idx];
        float xc,yc,r; ageom(a,xc,yc,r);
        int ng = p.gmax[b];
        float best=3.9e38f, biou=0.f;
        for (int g=0; g<ng; ++g){
          float4 gbb = p.gtb[b*GG+g], gcc = p.gtc[b*GG+g];
          float cost, iou = 0.f;
          if (gcc.w != 0.f){
            float tlx=fmaxf(gbb.x,bx.x), tly=fmaxf(gbb.y,bx.y);
            float brx=fminf(gbb.z,bx.z), bry=fminf(gbb.w,bx.w);
            float iw=fmaxf(brx-tlx,0.f), ih=fmaxf(bry-tly,0.f);
            float inter=iw*ih;
            iou = inter/(gcc.z + mt.x - inter + 1e-12f);
            bool inb=(xc>gbb.x)&&(xc<gbb.z)&&(yc>gbb.y)&&(yc<gbb.w);
            bool inc=(fabsf(xc-gcc.x)<r)&&(fabsf(yc-gcc.y)<r);
            cost = mt.y + 3.f*(-logf(iou+1e-8f)) + ((inb&&inc)?0.f:100000.f);
          } else cost = 1e9f;
          if (cost < best){ best=cost; biou=iou; }   // first-index argmin
        }
        iouv = biou;
      }
      float z = mt.w;
      float e = expf(-fabsf(z));
      float spz = fmaxf(z,0.f)+log1pf(e);
      float spn = fmaxf(-z,0.f)+log1pf(e);
      bce = iouv*spn + (1.f-iouv)*spz;
      fgv = 1.f;
    }
  }
  for (int off=32; off; off>>=1){
    bce += __shfl_xor(bce, off);
    fgv += __shfl_xor(fgv, off);
  }
  __shared__ float s_b[4], s_f[4];
  int lane = t & 63, wid = t >> 6;
  if (lane==0){ s_b[wid]=bce; s_f[wid]=fgv; }
  __syncthreads();
  if (t==0){
    // disjoint per-block partials: no atomics, no fences, no hot cache line
    p.pb[blockIdx.x] = s_b[0]+s_b[1]+s_b[2]+s_b[3];
    p.pf[blockIdx.x] = s_f[0]+s_f[1]+s_f[2]+s_f[3];
  }
}

// ---- kD: reduce 1050 partials + finalize (1 block) -------------------------
__global__ __launch_bounds__(TPB) void kD(P p){
  int t = threadIdx.x;
  float sb=0.f, sf=0.f;
  for (int i = t; i < NBLK; i += TPB){ sb += p.pb[i]; sf += p.pf[i]; }
#pragma unroll
  for (int off=32; off; off>>=1){
    sb += __shfl_xor(sb, off);
    sf += __shfl_xor(sf, off);
  }
  __shared__ float s_b[4], s_f[4];
  int lane = t & 63, wid = t >> 6;
  if (lane==0){ s_b[wid]=sb; s_f[wid]=sf; }
  __syncthreads();
  if (t==0){
    float tb=s_b[0]+s_b[1]+s_b[2]+s_b[3];
    float tf=s_f[0]+s_f[1]+s_f[2]+s_f[3];
    p.out[0] = tb / fmaxf(tf, 1.f);
  }
}

extern "C" void kernel_launch(void* const* d_in, const int* in_sizes, int n_in,
                              void* d_out, int out_size, void* d_ws, size_t ws_size,
                              hipStream_t stream) {
  P p;
  p.outs = d_in[0];
  p.labs = d_in[1];
  p.ss   = d_in[4];
  char* w = (char*)d_ws;
  p.box4  = (float4*)w; w += (size_t)BA*sizeof(float4);
  p.meta4 = (float4*)w; w += (size_t)BA*sizeof(float4);
  p.cbox  = (float4*)w; w += (size_t)BA*sizeof(float4);
  p.cmeta = (float4*)w; w += (size_t)BA*sizeof(float4);
  p.gtb   = (float4*)w; w += (size_t)NG*sizeof(float4);
  p.gtc   = (float4*)w; w += (size_t)NG*sizeof(float4);
  p.miou  = (float*)w;  w += (size_t)BA*sizeof(float);
  p.cnt   = (int*)w;    w += (size_t)BA*sizeof(int);
  p.gmax  = (int*)w;    w += (size_t)BB*sizeof(int);
  p.nfg   = (int*)w;    w += (size_t)BB*sizeof(int);
  p.chunkcnt = (int*)w; w += (size_t)BB*NCH*sizeof(int);
  p.pb    = (float*)w;  w += (size_t)NBLK*sizeof(float);
  p.pf    = (float*)w;  w += (size_t)NBLK*sizeof(float);
  p.out   = (float*)d_out;

  kA<<<dim3(NCH, BB), TPB, 0, stream>>>(p);
  kE<<<dim3(NCH, BB), TPB, 0, stream>>>(p);
  kB<<<BB*GG, TPK, 0, stream>>>(p);
  kCD<<<NBLK, TPB, 0, stream>>>(p);
  kD<<<1, TPB, 0, stream>>>(p);
}

// Round 16
// 218.290 us; speedup vs baseline: 1.0316x; 1.0316x over previous
//
#include <hip/hip_runtime.h>
#include <hip/hip_bf16.h>
#include <stdint.h>

#define BB 32
#define GG 100
#define AA 8400
#define TPB 256
#define NCH 33                         // ceil(8400/256) chunks per image
#define TPK 512
#define MAXJ 17                        // ceil(8400/512) slots per thread (max)
#define BA (BB*AA)
#define NG (BB*GG)
#define NBLK (BA/TPB)                  // 1050 kCD blocks

typedef __hip_bfloat16 bf16;

struct P {
  const void *outs, *labs, *ss;
  float4 *box4, *meta4, *gtb, *gtc;   // per-anchor box/meta; per-gt box/center
  float4 *cbox, *cmeta;               // per-image compacted fg anchors
  float *miou, *pb, *pf;              // per-block BCE / fg partials (no atomics)
  int *cnt, *gmax, *nfg, *chunkcnt;
  float *out;
};

// runtime input-dtype detection: strides[0]==8.0
// f32 word 0x41000000 ; bf16 pair (8.0,8.0) 0x41004100
__device__ __forceinline__ int dtypeFlag(const void* ss){
  return (((const uint32_t*)ss)[0] == 0x41000000u) ? 1 : 0;
}
__device__ __forceinline__ float ld(const void* p, int i, int isf32){
  return isf32 ? ((const float*)p)[i] : __bfloat162float(((const bf16*)p)[i]);
}
// analytic anchor geometry (exact: ints + pow2 strides exact in f32/bf16)
__device__ __forceinline__ void ageom(int a, float& xc, float& yc, float& r){
  int x, y, s;
  if (a < 6400){ x = a % 80; y = a / 80; s = 8; }
  else if (a < 8000){ int q = a - 6400; x = q % 40; y = q / 40; s = 16; }
  else { int q = a - 8000; x = q % 20; y = q / 20; s = 32; }
  float fs = (float)s;
  xc = ((float)x + 0.5f) * fs;
  yc = ((float)y + 0.5f) * fs;
  r  = 2.5f * fs;
}
__device__ __forceinline__ uint32_t apack(int a){
  int x, y, s;
  if (a < 6400){ x = a % 80; y = a / 80; s = 8; }
  else if (a < 8000){ int q = a - 6400; x = q % 40; y = q / 40; s = 16; }
  else { int q = a - 8000; x = q % 20; y = q / 20; s = 32; }
  uint32_t ix = (uint32_t)(x*s + s/2), iy = (uint32_t)(y*s + s/2);
  return ix | (iy << 16);
}

// ---- kA: gt structs (self-computed) + per-anchor staging + fg + chunk count
__global__ __launch_bounds__(TPB) void kA(P p){
  __shared__ float4 s_gtb[GG], s_gtc[GG];
  __shared__ float s_o[TPB*6];
  __shared__ int s_w[4];
  __shared__ int s_ng;
  int t = threadIdx.x;
  int c = blockIdx.x, b = blockIdx.y;
  int isf = dtypeFlag(p.ss);
  if (t == 0) s_ng = 0;
  int nel = min(TPB*6, AA*6 - c*(TPB*6));      // floats in this chunk
  if (isf){
    const float4* src = (const float4*)((const float*)p.outs + (size_t)b*AA*6 + (size_t)c*(TPB*6));
    float4* dst = (float4*)s_o;
    for (int i = t; i < nel/4; i += TPB) dst[i] = src[i];
  } else {
    const uint4* src = (const uint4*)((const bf16*)p.outs + (size_t)b*AA*6 + (size_t)c*(TPB*6));
    for (int i = t; i < nel/8; i += TPB){
      uint4 u = src[i];
      int o = i*8;
      s_o[o+0]=__uint_as_float(u.x<<16); s_o[o+1]=__uint_as_float(u.x&0xffff0000u);
      s_o[o+2]=__uint_as_float(u.y<<16); s_o[o+3]=__uint_as_float(u.y&0xffff0000u);
      s_o[o+4]=__uint_as_float(u.z<<16); s_o[o+5]=__uint_as_float(u.z&0xffff0000u);
      s_o[o+6]=__uint_as_float(u.w<<16); s_o[o+7]=__uint_as_float(u.w&0xffff0000u);
    }
  }
  __syncthreads();
  if (t < GG){
    int i = b*GG + t;
    float l0 = ld(p.labs, i*5  , isf);
    float gcx= ld(p.labs, i*5+1, isf);
    float gcy= ld(p.labs, i*5+2, isf);
    float gw = ld(p.labs, i*5+3, isf);
    float gh = ld(p.labs, i*5+4, isf);
    int valid = (l0+gcx+gcy+gw+gh) > 0.f;
    float4 vb = make_float4(gcx-gw*0.5f, gcy-gh*0.5f, gcx+gw*0.5f, gcy+gh*0.5f);
    float4 vc = make_float4(gcx, gcy, gw*gh, valid ? 1.f : 0.f);
    s_gtb[t] = vb; s_gtc[t] = vc;
    if (c == 0){ p.gtb[i] = vb; p.gtc[i] = vc; }
    if (valid) atomicMax(&s_ng, t+1);
  }
  __syncthreads();
  int ng = s_ng;
  if (c == 0 && t == 0) p.gmax[b] = ng;
  int a = c*TPB + t;
  int fg = 0;
  if (a < AA){
    float cx=s_o[t*6], cy=s_o[t*6+1], w=s_o[t*6+2], h=s_o[t*6+3], ob=s_o[t*6+4], cl=s_o[t*6+5];
    int idx = b*AA + a;
    p.box4[idx] = make_float4(cx-w*0.5f, cy-h*0.5f, cx+w*0.5f, cy+h*0.5f);
    float so = 1.f/(1.f+expf(-ob));
    float sc = 1.f/(1.f+expf(-cl));
    float pcc = -logf(sqrtf(sc*so) + 1e-9f);
    float xc, yc, r; ageom(a, xc, yc, r);
    for (int g = 0; g < ng; ++g){
      float4 gb = s_gtb[g], gc = s_gtc[g];
      bool inb = (xc>gb.x)&&(xc<gb.z)&&(yc>gb.y)&&(yc<gb.w);
      bool inc = (fabsf(xc-gc.x)<r)&&(fabsf(yc-gc.y)<r);
      fg |= (gc.w != 0.f) && (inb||inc);
    }
    p.meta4[idx] = make_float4(w*h, pcc, fg ? 1.f : 0.f, cl);
    p.cnt[idx] = 0;
  }
  int lane = t & 63, wid = t >> 6;
  unsigned long long m = __ballot(fg);
  if (lane == 0) s_w[wid] = __popcll(m);
  __syncthreads();
  if (t == 0) p.chunkcnt[b*NCH + c] = s_w[0]+s_w[1]+s_w[2]+s_w[3];
}

// ---- kE: parallel order-preserving fg compaction (one block per chunk) -----
__global__ __launch_bounds__(TPB) void kE(P p){
  __shared__ int s_off;
  __shared__ int s_w[4];
  int t = threadIdx.x, c = blockIdx.x, b = blockIdx.y;
  int lane = t & 63, wid = t >> 6;
  if (wid == 0){
    int v = (lane < c) ? p.chunkcnt[b*NCH + lane] : 0;   // c <= 32 < 64 lanes
#pragma unroll
    for (int off=32; off; off>>=1) v += __shfl_xor(v, off);
    if (lane == 0) s_off = v;
  }
  int a = c*TPB + t;
  float4 mt = make_float4(0,0,0,0);
  int fg = 0;
  if (a < AA){ mt = p.meta4[b*AA+a]; fg = (mt.z != 0.f) ? 1 : 0; }
  unsigned long long m = __ballot(fg);
  int rank = __popcll(m & ((1ull<<lane)-1ull));
  if (lane == 0) s_w[wid] = __popcll(m);
  __syncthreads();
  int off = s_off;
  for (int w2 = 0; w2 < wid; ++w2) off += s_w[w2];
  if (fg){
    int pos = off + rank;
    p.cbox [b*AA+pos] = p.box4[b*AA+a];
    // cmeta: (area, pcc, a, packed int centers)
    p.cmeta[b*AA+pos] = make_float4(mt.x, mt.y, __int_as_float(a),
                                    __uint_as_float(apack(a)));
  }
  if (c == NCH-1 && t == 0)
    p.nfg[b] = s_off + s_w[0]+s_w[1]+s_w[2]+s_w[3];
}

// ---- kB: per-(b,g) dyn_k + selection; LDS slots, runtime nj, fused pops ----
__global__ __launch_bounds__(TPK) void kB(P p){
  __shared__ float s_slot[MAXJ*TPK];   // 34.8 KB: [j*TPK + t]
  __shared__ float s_v[2][8];
  __shared__ int   s_i[2][8];
  __shared__ int   s_selA[10];
  int t = threadIdx.x;
  int b = blockIdx.x / GG, g = blockIdx.x % GG;
  float4 gc = p.gtc[b*GG+g];
  if (gc.w == 0.f) return;                 // uniform, pre-barrier
  float4 gb = p.gtb[b*GG+g];
  float glx=gb.x, gly=gb.y, ghx=gb.z, ghy=gb.w, gcx=gc.x, gcy=gc.y, ga=gc.z;
  int base = b*AA;
  int nfg = p.nfg[b];
  int nj = (nfg + TPK - 1) / TPK;          // runtime bound (~6), not MAXJ=17
  if (t < 10) s_selA[t] = -1;
  int lane = t & 63, wid = t >> 6;

  // main pass: iou into LDS column slots
  float lmax = -1.f;
  for (int j=0;j<nj;j++){
    int pos = j*TPK + t;
    float v = -1.f;
    if (pos < nfg){
      float4 mt = p.cmeta[base+pos];
      float4 bx = p.cbox [base+pos];
      float tlx=fmaxf(glx,bx.x), tly=fmaxf(gly,bx.y);
      float brx=fminf(ghx,bx.z), bry=fminf(ghy,bx.w);
      float iw=fmaxf(brx-tlx,0.f), ih=fmaxf(bry-tly,0.f);
      float inter=iw*ih;
      v = inter/(ga + mt.x - inter + 1e-12f);
    }
    s_slot[pos] = v;
    lmax = fmaxf(lmax, v);
  }

  // phase 1: top-10 iou sum, descending (values only; == jnp top_k sum order)
  float sum = 0.f;
  for (int k=0;k<10;k++){
    float wv = lmax;
#pragma unroll
    for (int off=32; off; off>>=1) wv = fmaxf(wv, __shfl_xor(wv, off));
    if (lane==0) s_v[k&1][wid] = wv;
    __syncthreads();
    float gv = -2.f;
#pragma unroll
    for (int w2=0;w2<8;w2++) gv = fmaxf(gv, s_v[k&1][w2]);
    if (gv <= 0.f) break;                  // remaining top-k terms are 0
    sum += gv;
    int ow = 0;
#pragma unroll
    for (int w2=7;w2>=0;w2--) if (s_v[k&1][w2] == gv) ow = w2;  // first wave
    if (wid == ow){
      unsigned long long ms = __ballot(lmax == gv);
      if ((int)(__ffsll(ms) - 1) == lane){ // unique owner: fused find+flip+rescan
        int pm = -1; float nl = -1.f;
        for (int j=0;j<nj;j++){
          int pos = j*TPK+t;
          float vv = s_slot[pos];
          if (pm < 0 && vv == gv){ pm = pos; vv = -gv; s_slot[pos] = vv; }
          nl = fmaxf(nl, vv);
        }
        lmax = nl;
      }
    }
  }
  int dk = (int)sum; if (dk<1) dk=1; if (dk>10) dk=10;

  // phase 2: recompute cost into same slots (iou = |slot|, bit-exact)
  float lcv = 3.0e38f; int lci = 0x7fffffff;
  for (int j=0;j<nj;j++){
    int pos = j*TPK + t;
    float cst = 3.0e38f;
    if (pos < nfg){
      float iou = fabsf(s_slot[pos]);
      float4 mt = p.cmeta[base+pos];
      uint32_t u = __float_as_uint(mt.w);
      float xc = (float)(u & 0xffffu), yc = (float)(u >> 16);
      int a = __float_as_int(mt.z);
      float r = (a < 6400) ? 20.f : ((a < 8000) ? 40.f : 80.f);
      bool inb=(xc>glx)&&(xc<ghx)&&(yc>gly)&&(yc<ghy);
      bool inc=(fabsf(xc-gcx)<r)&&(fabsf(yc-gcy)<r);
      cst = mt.y + 3.f*(-logf(iou+1e-8f)) + ((inb&&inc)?0.f:100000.f);
    }
    s_slot[pos] = cst;
    if (cst < lcv){ lcv = cst; lci = pos; }    // asc pos => first-tie kept
  }
  __syncthreads();                         // recompute fence + parity reuse

  for (int k=0;k<dk;k++){
    float bv = lcv; int bi = lci;
#pragma unroll
    for (int off=32; off; off>>=1){
      float ov=__shfl_xor(bv,off); int oi=__shfl_xor(bi,off);
      if (ov<bv || (ov==bv && oi<bi)){ bv=ov; bi=oi; }
    }
    if (lane==0){ s_v[k&1][wid]=bv; s_i[k&1][wid]=bi; }
    __syncthreads();
    float gv=s_v[k&1][0]; int gi=s_i[k&1][0];
#pragma unroll
    for (int w2=1;w2<8;w2++){
      float ov=s_v[k&1][w2]; int oi=s_i[k&1][w2];
      if (ov<gv || (ov==gv && oi<gi)){ gv=ov; gi=oi; }
    }
    if (gv >= 2.9e38f) break;              // candidates exhausted
    if ((gi & (TPK-1)) == t){              // unique owner: record + pop + rescan
      s_selA[k] = gi;
      s_slot[gi] = 3.0e38f;
      float nv = 3.0e38f; int ni = 0x7fffffff;
      for (int j=0;j<nj;j++){
        int pos = j*TPK+t;
        float vv = s_slot[pos];
        if (vv < nv){ nv=vv; ni=pos; }
      }
      lcv=nv; lci=ni;
    }
  }
  __syncthreads();
  if (t < dk){
    int pos = s_selA[t];                   // t-th smallest (cost,pos)
    if (pos >= 0){
      float4 mt = p.cmeta[base+pos];
      float4 bx = p.cbox [base+pos];
      int a = __float_as_int(mt.z);
      float tlx=fmaxf(glx,bx.x), tly=fmaxf(gly,bx.y);
      float brx=fminf(ghx,bx.z), bry=fminf(ghy,bx.w);
      float iw=fmaxf(brx-tlx,0.f), ih=fmaxf(bry-tly,0.f);
      float inter=iw*ih;
      float iou=inter/(ga + mt.x - inter + 1e-12f);
      atomicAdd(&p.cnt[base+a], 1);
      p.miou[base+a] = iou;                // races only when cnt>1; kCD recomputes
    }
  }
}

// ---- kCD: conflict resolution + masked BCE -> per-block partials -----------
__global__ __launch_bounds__(TPB) void kCD(P p){
  int t = threadIdx.x;
  int idx = blockIdx.x*TPB + t;
  float bce=0.f, fgv=0.f;
  if (idx < BA){
    int cgt = p.cnt[idx];
    if (cgt > 0){
      int b = idx/AA, a = idx - b*AA;
      float4 mt = p.meta4[idx];
      float iouv;
      if (cgt == 1){ iouv = p.miou[idx]; }
      else {
        float4 bx = p.box4[idx];
        float xc,yc,r; ageom(a,xc,yc,r);
        int ng = p.gmax[b];
        float best=3.9e38f, biou=0.f;
        for (int g=0; g<ng; ++g){
          float4 gbb = p.gtb[b*GG+g], gcc = p.gtc[b*GG+g];
          float cost, iou = 0.f;
          if (gcc.w != 0.f){
            float tlx=fmaxf(gbb.x,bx.x), tly=fmaxf(gbb.y,bx.y);
            float brx=fminf(gbb.z,bx.z), bry=fminf(gbb.w,bx.w);
            float iw=fmaxf(brx-tlx,0.f), ih=fmaxf(bry-tly,0.f);
            float inter=iw*ih;
            iou = inter/(gcc.z + mt.x - inter + 1e-12f);
            bool inb=(xc>gbb.x)&&(xc<gbb.z)&&(yc>gbb.y)&&(yc<gbb.w);
            bool inc=(fabsf(xc-gcc.x)<r)&&(fabsf(yc-gcc.y)<r);
            cost = mt.y + 3.f*(-logf(iou+1e-8f)) + ((inb&&inc)?0.f:100000.f);
          } else cost = 1e9f;
          if (cost < best){ best=cost; biou=iou; }   // first-index argmin
        }
        iouv = biou;
      }
      float z = mt.w;
      float e = expf(-fabsf(z));
      float spz = fmaxf(z,0.f)+log1pf(e);
      float spn = fmaxf(-z,0.f)+log1pf(e);
      bce = iouv*spn + (1.f-iouv)*spz;
      fgv = 1.f;
    }
  }
  for (int off=32; off; off>>=1){
    bce += __shfl_xor(bce, off);
    fgv += __shfl_xor(fgv, off);
  }
  __shared__ float s_b[4], s_f[4];
  int lane = t & 63, wid = t >> 6;
  if (lane==0){ s_b[wid]=bce; s_f[wid]=fgv; }
  __syncthreads();
  if (t==0){
    // disjoint per-block partials: no atomics, no fences, no hot cache line
    p.pb[blockIdx.x] = s_b[0]+s_b[1]+s_b[2]+s_b[3];
    p.pf[blockIdx.x] = s_f[0]+s_f[1]+s_f[2]+s_f[3];
  }
}

// ---- kD: reduce 1050 partials + finalize (1 block) -------------------------
__global__ __launch_bounds__(TPB) void kD(P p){
  int t = threadIdx.x;
  float sb=0.f, sf=0.f;
  for (int i = t; i < NBLK; i += TPB){ sb += p.pb[i]; sf += p.pf[i]; }
#pragma unroll
  for (int off=32; off; off>>=1){
    sb += __shfl_xor(sb, off);
    sf += __shfl_xor(sf, off);
  }
  __shared__ float s_b[4], s_f[4];
  int lane = t & 63, wid = t >> 6;
  if (lane==0){ s_b[wid]=sb; s_f[wid]=sf; }
  __syncthreads();
  if (t==0){
    float tb=s_b[0]+s_b[1]+s_b[2]+s_b[3];
    float tf=s_f[0]+s_f[1]+s_f[2]+s_f[3];
    p.out[0] = tb / fmaxf(tf, 1.f);
  }
}

extern "C" void kernel_launch(void* const* d_in, const int* in_sizes, int n_in,
                              void* d_out, int out_size, void* d_ws, size_t ws_size,
                              hipStream_t stream) {
  P p;
  p.outs = d_in[0];
  p.labs = d_in[1];
  p.ss   = d_in[4];
  char* w = (char*)d_ws;
  p.box4  = (float4*)w; w += (size_t)BA*sizeof(float4);
  p.meta4 = (float4*)w; w += (size_t)BA*sizeof(float4);
  p.cbox  = (float4*)w; w += (size_t)BA*sizeof(float4);
  p.cmeta = (float4*)w; w += (size_t)BA*sizeof(float4);
  p.gtb   = (float4*)w; w += (size_t)NG*sizeof(float4);
  p.gtc   = (float4*)w; w += (size_t)NG*sizeof(float4);
  p.miou  = (float*)w;  w += (size_t)BA*sizeof(float);
  p.cnt   = (int*)w;    w += (size_t)BA*sizeof(int);
  p.gmax  = (int*)w;    w += (size_t)BB*sizeof(int);
  p.nfg   = (int*)w;    w += (size_t)BB*sizeof(int);
  p.chunkcnt = (int*)w; w += (size_t)BB*NCH*sizeof(int);
  p.pb    = (float*)w;  w += (size_t)NBLK*sizeof(float);
  p.pf    = (float*)w;  w += (size_t)NBLK*sizeof(float);
  p.out   = (float*)d_out;

  kA<<<dim3(NCH, BB), TPB, 0, stream>>>(p);
  kE<<<dim3(NCH, BB), TPB, 0, stream>>>(p);
  kB<<<BB*GG, TPK, 0, stream>>>(p);
  kCD<<<NBLK, TPB, 0, stream>>>(p);
  kD<<<1, TPB, 0, stream>>>(p);
}